// Round 1
// 1310.038 us; speedup vs baseline: 1.0055x; 1.0055x over previous
//
#include <hip/hip_runtime.h>
#include <stdint.h>

// GNN_graphpred: N=524288 nodes, E=1048576 edges (paired), D=128, G=16384 graphs.
// Factored pipeline (5 launches):
//   g = segment_mean(x, batch)                       [G,128] f32   (k_segmean)
//   prep: transposed bf16 weights WnT/WnbT/WpT/WsT/WeT             (k_prep)
//   h = g @ Wn_bot + b_node ; out3 = g @ W_pool + bp [G,128] f32   (k_small, one launch)
//   out0 = nr = mish(x @ Wn_top + h[batch])          [N,128]       (k_node pass 1)
//   out1 = mish(nr @ (We_top+We_bot) + b_edge)       [N,128]       (k_node pass 2, fused:
//                                                     nr tile restaged LDS-only, no re-read)
//   out2 = pair-avg mish([nr[src]|nr[dst]] @ We + b) [E/2,128]     (k_edge, 2 K-phases,
//                                                     phase-1 gather prefetched into regs)

#define D128 128
#define NG 16384

typedef __attribute__((ext_vector_type(8))) short short8;   // 8 bf16 (4 VGPRs)
typedef __attribute__((ext_vector_type(4))) float f32x4;    // MFMA accumulator

__device__ __forceinline__ unsigned short f2bf(float f) {
  union { float f; unsigned int u; } v; v.f = f;
  unsigned int u = v.u;
  return (unsigned short)((u + 0x7fffu + ((u >> 16) & 1u)) >> 16);  // RNE
}

__device__ __forceinline__ float mish_f(float v) {
  // mish(v) = v * tanh(softplus(v)) = v * (u^2+2u)/(u^2+2u+2), u = e^v (clamped)
  float u = __expf(fminf(v, 20.0f));
  float n = u * u + 2.0f * u;
  return v * n / (n + 2.0f);
}

// XOR-swizzled LDS offset (elements) for 128x128 bf16 tile, 16B chunks.
// row r (0..127), chunk c (0..15, 8 bf16 each). 2-way bank aliasing only (free).
__device__ __forceinline__ int swz(int r, int c) {
  return r * 128 + (((c ^ r) & 15) << 3);
}

// ---------------- segment mean (batch is sorted) ----------------
__global__ void k_segmean(const float* __restrict__ x, const int* __restrict__ batch,
                          float* __restrict__ g, int N) {
  int gi = blockIdx.x;
  int lo = 0, hi = N;
  while (lo < hi) { int mid = (lo + hi) >> 1; if (batch[mid] < gi) lo = mid + 1; else hi = mid; }
  int start = lo;
  hi = N;
  while (lo < hi) { int mid = (lo + hi) >> 1; if (batch[mid] < gi + 1) lo = mid + 1; else hi = mid; }
  int end = lo;
  float s = 0.f;
  for (int r = start; r < end; ++r) s += x[(size_t)r * D128 + threadIdx.x];
  float cnt = (float)(end - start);
  g[(size_t)gi * D128 + threadIdx.x] = s / fmaxf(cnt, 1.0f);
}

// ---------------- weight prep: transpose + bf16 ----------------
__global__ void k_prep(const float* __restrict__ Wn, const float* __restrict__ We,
                       const float* __restrict__ Wp,
                       unsigned short* __restrict__ WnT, unsigned short* __restrict__ WnbT,
                       unsigned short* __restrict__ WpT, unsigned short* __restrict__ WsT,
                       unsigned short* __restrict__ WeT) {
  int id = blockIdx.x * 256 + threadIdx.x;
  if (id < 16384) {
    int n = id >> 7, k = id & 127;
    WnT[n * 128 + k] = f2bf(Wn[k * 128 + n]);
  } else if (id < 32768) {
    int t = id - 16384; int n = t >> 7, k = t & 127;
    WnbT[n * 128 + k] = f2bf(Wn[(k + 128) * 128 + n]);
  } else if (id < 49152) {
    int t = id - 32768; int n = t >> 7, k = t & 127;
    WpT[n * 128 + k] = f2bf(Wp[k * 128 + n]);
  } else if (id < 65536) {
    int t = id - 49152; int n = t >> 7, k = t & 127;
    WsT[n * 128 + k] = f2bf(We[k * 128 + n] + We[(k + 128) * 128 + n]);
  } else if (id < 98304) {
    int t = id - 65536; int n = t >> 8, k = t & 255;
    WeT[n * 256 + k] = f2bf(We[k * 128 + n]);
  }
}

// ---- shared MFMA helpers -------------------------------------------------
__device__ __forceinline__ void stage_f32(unsigned short* lds, const float* src, int r0, int tid) {
#pragma unroll
  for (int it = 0; it < 8; ++it) {
    int id = it * 256 + tid;
    int r = id >> 4, c = id & 15;
    const float* p = src + (size_t)(r0 + r) * D128 + c * 8;
    float4 v0 = *(const float4*)p;
    float4 v1 = *(const float4*)(p + 4);
    short8 pk;
    pk[0] = (short)f2bf(v0.x); pk[1] = (short)f2bf(v0.y);
    pk[2] = (short)f2bf(v0.z); pk[3] = (short)f2bf(v0.w);
    pk[4] = (short)f2bf(v1.x); pk[5] = (short)f2bf(v1.y);
    pk[6] = (short)f2bf(v1.z); pk[7] = (short)f2bf(v1.w);
    *(short8*)&lds[swz(r, c)] = pk;
  }
}
__device__ __forceinline__ void stage_bf16(unsigned short* lds, const unsigned short* src,
                                           int stride, int k0, int tid) {
#pragma unroll
  for (int it = 0; it < 8; ++it) {
    int id = it * 256 + tid;
    int r = id >> 4, c = id & 15;
    *(short8*)&lds[swz(r, c)] = *(const short8*)(src + (size_t)r * stride + k0 + c * 8);
  }
}

#define MFMA_K128(A_lds, W_lds, acc, wr, wc, l15, quad)                                   \
  do {                                                                                    \
    _Pragma("unroll")                                                                     \
    for (int kc = 0; kc < 4; ++kc) {                                                      \
      short8 afr[4], bfr[4];                                                              \
      _Pragma("unroll")                                                                   \
      for (int i = 0; i < 4; ++i) afr[i] = *(const short8*)&A_lds[swz(wr + i*16 + l15, kc*4 + quad)]; \
      _Pragma("unroll")                                                                   \
      for (int j = 0; j < 4; ++j) bfr[j] = *(const short8*)&W_lds[swz(wc + j*16 + l15, kc*4 + quad)]; \
      _Pragma("unroll")                                                                   \
      for (int i = 0; i < 4; ++i)                                                         \
        _Pragma("unroll")                                                                 \
        for (int j = 0; j < 4; ++j)                                                       \
          acc[i][j] = __builtin_amdgcn_mfma_f32_16x16x32_bf16(afr[i], bfr[j], acc[i][j], 0, 0, 0); \
    }                                                                                     \
  } while (0)

// ---------------- small GEMMs: h = g@WnbT + bn ; out3 = g@WpT + bp ----------------
// One launch, 256 blocks (full CU coverage): blocks 0..127 -> h, 128..255 -> out3.
__global__ __launch_bounds__(256, 2)
void k_small(const float* __restrict__ g,
             const unsigned short* __restrict__ WnbT, const float* __restrict__ bn,
             float* __restrict__ h,
             const unsigned short* __restrict__ WpT, const float* __restrict__ bp,
             float* __restrict__ out3) {
  __shared__ unsigned short A_lds[16384];
  __shared__ unsigned short W_lds[16384];
  int tid = threadIdx.x;
  bool second = blockIdx.x >= 128;
  int m0 = (blockIdx.x & 127) * 128;
  const unsigned short* Wt = second ? WpT : WnbT;
  const float* bias = second ? bp : bn;
  float* out = second ? out3 : h;
  stage_f32(A_lds, g, m0, tid);
  stage_bf16(W_lds, Wt, 128, 0, tid);
  __syncthreads();
  int wave = tid >> 6, lane = tid & 63, l15 = lane & 15, quad = lane >> 4;
  int wr = (wave >> 1) * 64, wc = (wave & 1) * 64;
  f32x4 acc[4][4] = {};
  MFMA_K128(A_lds, W_lds, acc, wr, wc, l15, quad);
#pragma unroll
  for (int i = 0; i < 4; ++i) {
#pragma unroll
    for (int rr = 0; rr < 4; ++rr) {
      int grow = m0 + wr + i * 16 + quad * 4 + rr;
#pragma unroll
      for (int j = 0; j < 4; ++j) {
        int col = wc + j * 16 + l15;
        out[(size_t)grow * D128 + col] = acc[i][j][rr] + bias[col];
      }
    }
  }
}

// ---------------- fused node GEMM: out0 = mish(x@WnT^T + h[batch]);
//                  out1 = mish(bf16(out0) @ WsT^T + be)  (nr tile restaged via LDS) ------
template <bool WRITE_BF16>
__global__ __launch_bounds__(256, 2)
void k_node(const float* __restrict__ x, const int* __restrict__ batch,
            const float* __restrict__ h, const unsigned short* __restrict__ WnT,
            const unsigned short* __restrict__ WsT, const float* __restrict__ be,
            float* __restrict__ out0, float* __restrict__ out1,
            unsigned short* __restrict__ nrb) {
  __shared__ unsigned short A_lds[16384];
  __shared__ unsigned short W_lds[16384];
  int tid = threadIdx.x;
  int m0 = blockIdx.x * 128;
  stage_f32(A_lds, x, m0, tid);
  stage_bf16(W_lds, WnT, 128, 0, tid);
  __syncthreads();
  int wave = tid >> 6, lane = tid & 63, l15 = lane & 15, quad = lane >> 4;
  int wr = (wave >> 1) * 64, wc = (wave & 1) * 64;
  f32x4 acc[4][4] = {};
  MFMA_K128(A_lds, W_lds, acc, wr, wc, l15, quad);
  __syncthreads();                       // all pass-1 LDS reads done
  stage_bf16(W_lds, WsT, 128, 0, tid);   // W for pass 2 (issued early, drains at barrier)
  // epilogue 1: nr = mish(acc + h[batch]); write out0 (+nrb); restage bf16 nr into A_lds
#pragma unroll
  for (int i = 0; i < 4; ++i) {
#pragma unroll
    for (int rr = 0; rr < 4; ++rr) {
      int r = wr + i * 16 + quad * 4 + rr;
      int grow = m0 + r;
      int b = batch[grow];
      const float* hrow = h + (size_t)b * D128;
#pragma unroll
      for (int j = 0; j < 4; ++j) {
        int col = wc + j * 16 + l15;
        float m = mish_f(acc[i][j][rr] + hrow[col]);
        unsigned short mb = f2bf(m);
        out0[(size_t)grow * D128 + col] = m;
        if (WRITE_BF16) nrb[(size_t)grow * D128 + col] = mb;
        A_lds[swz(r, col >> 3) + (col & 7)] = mb;
      }
    }
  }
  __syncthreads();
  f32x4 acc2[4][4] = {};
  MFMA_K128(A_lds, W_lds, acc2, wr, wc, l15, quad);
#pragma unroll
  for (int i = 0; i < 4; ++i) {
#pragma unroll
    for (int rr = 0; rr < 4; ++rr) {
      int grow = m0 + wr + i * 16 + quad * 4 + rr;
#pragma unroll
      for (int j = 0; j < 4; ++j) {
        int col = wc + j * 16 + l15;
        out1[(size_t)grow * D128 + col] = mish_f(acc2[i][j][rr] + be[col]);
      }
    }
  }
}

// ---------------- edge GEMM: out2 = pairavg(mish([nr[src]|nr[dst]]@We + be)) ----------------
template <bool SRCB>
__global__ __launch_bounds__(256, 2)
void k_edge(const void* __restrict__ src, const int* __restrict__ eidx, int E,
            const unsigned short* __restrict__ WeT, const float* __restrict__ be,
            float* __restrict__ out2) {
  __shared__ unsigned short A_lds[16384];
  __shared__ unsigned short W_lds[16384];
  int tid = threadIdx.x;
  int e0 = blockIdx.x * 128;
  int wave = tid >> 6, lane = tid & 63, l15 = lane & 15, quad = lane >> 4;
  int wr = (wave >> 1) * 64, wc = (wave & 1) * 64;
  f32x4 acc[4][4] = {};
  if (SRCB) {
    const unsigned short* s = (const unsigned short*)src;
    // phase 0: gather-stage src endpoints + W top half
#pragma unroll
    for (int it = 0; it < 8; ++it) {
      int id = it * 256 + tid;
      int r = id >> 4, c = id & 15;
      int row = eidx[e0 + r];
      *(short8*)&A_lds[swz(r, c)] = *(const short8*)(s + (size_t)row * D128 + c * 8);
    }
    stage_bf16(W_lds, WeT, 256, 0, tid);
    __syncthreads();
    // T14: prefetch phase-1 gather rows into registers; HBM latency hides under MFMA0
    short8 pre[8];
#pragma unroll
    for (int it = 0; it < 8; ++it) {
      int id = it * 256 + tid;
      int r = id >> 4, c = id & 15;
      int row = eidx[E + e0 + r];
      pre[it] = *(const short8*)(s + (size_t)row * D128 + c * 8);
    }
    MFMA_K128(A_lds, W_lds, acc, wr, wc, l15, quad);
    __syncthreads();   // phase-0 LDS reads done
#pragma unroll
    for (int it = 0; it < 8; ++it) {
      int id = it * 256 + tid;
      int r = id >> 4, c = id & 15;
      *(short8*)&A_lds[swz(r, c)] = pre[it];
    }
    stage_bf16(W_lds, WeT, 256, 128, tid);
    __syncthreads();
    MFMA_K128(A_lds, W_lds, acc, wr, wc, l15, quad);
  } else {
#pragma unroll
    for (int ph = 0; ph < 2; ++ph) {
      if (ph) __syncthreads();
#pragma unroll
      for (int it = 0; it < 8; ++it) {
        int id = it * 256 + tid;
        int r = id >> 4, c = id & 15;
        int row = eidx[ph * E + e0 + r];
        const float* p = (const float*)src + (size_t)row * D128 + c * 8;
        float4 v0 = *(const float4*)p;
        float4 v1 = *(const float4*)(p + 4);
        short8 pk;
        pk[0] = (short)f2bf(v0.x); pk[1] = (short)f2bf(v0.y);
        pk[2] = (short)f2bf(v0.z); pk[3] = (short)f2bf(v0.w);
        pk[4] = (short)f2bf(v1.x); pk[5] = (short)f2bf(v1.y);
        pk[6] = (short)f2bf(v1.z); pk[7] = (short)f2bf(v1.w);
        *(short8*)&A_lds[swz(r, c)] = pk;
      }
      stage_bf16(W_lds, WeT, 256, ph * 128, tid);
      __syncthreads();
      MFMA_K128(A_lds, W_lds, acc, wr, wc, l15, quad);
    }
  }
  // epilogue: bias + mish per edge, then average consecutive (fwd,bwd) pairs.
#pragma unroll
  for (int i = 0; i < 4; ++i) {
#pragma unroll
    for (int j = 0; j < 4; ++j) {
      int col = wc + j * 16 + l15;
      float bv = be[col];
      float m0v = mish_f(acc[i][j][0] + bv);
      float m1v = mish_f(acc[i][j][1] + bv);
      float m2v = mish_f(acc[i][j][2] + bv);
      float m3v = mish_f(acc[i][j][3] + bv);
      int rloc = wr + i * 16 + quad * 4;
      size_t p = (size_t)((e0 + rloc) >> 1);
      out2[p * D128 + col] = 0.5f * (m0v + m1v);
      out2[(p + 1) * D128 + col] = 0.5f * (m2v + m3v);
    }
  }
}

extern "C" void kernel_launch(void* const* d_in, const int* in_sizes, int n_in,
                              void* d_out, int out_size, void* d_ws, size_t ws_size,
                              hipStream_t stream) {
  const float* x  = (const float*)d_in[0];
  const int* batch = (const int*)d_in[1];
  const int* eidx  = (const int*)d_in[2];
  const float* Wn = (const float*)d_in[3];
  const float* bn = (const float*)d_in[4];
  const float* We = (const float*)d_in[5];
  const float* be = (const float*)d_in[6];
  const float* Wp = (const float*)d_in[7];
  const float* bp = (const float*)d_in[8];
  int N = in_sizes[0] / D128;   // 524288
  int E = in_sizes[2] / 2;      // 1048576

  float* out  = (float*)d_out;
  float* out0 = out;                                   // node_rep      [N,128]
  float* out1 = out0 + (size_t)N * D128;               // self_edge_rep [N,128]
  float* out2 = out1 + (size_t)N * D128;               // edge_rep      [E/2,128]
  float* out3 = out2 + (size_t)(E / 2) * D128;         // graph_rep     [G,128]

  char* w = (char*)d_ws;
  float* g = (float*)w;                 w += (size_t)NG * D128 * 4;
  float* h = (float*)w;                 w += (size_t)NG * D128 * 4;
  unsigned short* WnT  = (unsigned short*)w; w += 16384 * 2;
  unsigned short* WnbT = (unsigned short*)w; w += 16384 * 2;
  unsigned short* WpT  = (unsigned short*)w; w += 16384 * 2;
  unsigned short* WsT  = (unsigned short*)w; w += 16384 * 2;
  unsigned short* WeT  = (unsigned short*)w; w += 32768 * 2;
  unsigned short* nrb  = (unsigned short*)w; w += (size_t)N * D128 * 2;
  bool cache = ws_size >= (size_t)(w - (char*)d_ws);

  k_segmean<<<NG, 128, 0, stream>>>(x, batch, g, N);
  k_prep<<<384, 256, 0, stream>>>(Wn, We, Wp, WnT, WnbT, WpT, WsT, WeT);
  k_small<<<256, 256, 0, stream>>>(g, WnbT, bn, h, WpT, bp, out3);
  if (cache) {
    k_node<true><<<N / 128, 256, 0, stream>>>(x, batch, h, WnT, WsT, be, out0, out1, nrb);
    k_edge<true><<<E / 128, 256, 0, stream>>>(nrb, eidx, E, WeT, be, out2);
  } else {
    k_node<false><<<N / 128, 256, 0, stream>>>(x, batch, h, WnT, WsT, be, out0, out1, nullptr);
    k_edge<false><<<E / 128, 256, 0, stream>>>(out0, eidx, E, WeT, be, out2);
  }
}